// Round 4
// baseline (143.710 us; speedup 1.0000x reference)
//
#include <hip/hip_runtime.h>
#include <hip/hip_bf16.h>
#include <cstdint>
#include <cstddef>

// Problem constants (fixed by setup_inputs)
#define B_   8
#define N_   256
#define DEG_ 32
#define H_   768
#define NH_  12
#define E_   (B_*N_*DEG_)   // 65536
#define M_   (B_*N_)        // 2048

typedef __attribute__((ext_vector_type(8))) short short8;
typedef __attribute__((ext_vector_type(4))) float float4v;

static __device__ __forceinline__ short f2bf(float f) {
    __hip_bfloat16 h = __float2bfloat16(f);
    return *(short*)&h;
}
static __device__ __forceinline__ float bf2f(short s) {
    return __uint_as_float(((unsigned)(unsigned short)s) << 16);
}

// ---------- flat cast fp32 -> bf16 for X (768 blk), Ek (24 blk), Ev (24 blk) ----------
__global__ __launch_bounds__(256)
void cast_flat(const float* __restrict__ X, const float* __restrict__ Ek,
               const float* __restrict__ Ev, short* __restrict__ Xb,
               short* __restrict__ Ekb, short* __restrict__ Evb)
{
    const int bid = blockIdx.x;
    const float* src; short* dst; int base;
    if (bid < 768)      { src = X;  dst = Xb;  base = bid * 2048; }
    else if (bid < 792) { src = Ek; dst = Ekb; base = (bid - 768) * 2048; }
    else                { src = Ev; dst = Evb; base = (bid - 792) * 2048; }
    const int i = base + threadIdx.x * 8;
    const float4 a = *(const float4*)(src + i);
    const float4 b = *(const float4*)(src + i + 4);
    short8 o;
    o[0] = f2bf(a.x); o[1] = f2bf(a.y); o[2] = f2bf(a.z); o[3] = f2bf(a.w);
    o[4] = f2bf(b.x); o[5] = f2bf(b.y); o[6] = f2bf(b.z); o[7] = f2bf(b.w);
    *(short8*)(dst + i) = o;
}

// ------------- transpose + cast W[k][n] fp32 -> Wt[n][k] bf16 ------------------
__global__ __launch_bounds__(256)
void cast_wt(const float* __restrict__ W0, const float* __restrict__ W1,
             const float* __restrict__ W2, short* __restrict__ Wt)
{
    const float* W = (blockIdx.z == 0) ? W0 : (blockIdx.z == 1) ? W1 : W2;
    short* Wo = Wt + (size_t)blockIdx.z * H_ * H_;
    __shared__ short tile[64][65];
    const int kb = blockIdx.y * 64, nb = blockIdx.x * 64;
    const int t = threadIdx.x;
    {
        const int k = t >> 2, nq = (t & 3) * 16;
        const float* src = W + (size_t)(kb + k) * H_ + nb + nq;
        #pragma unroll
        for (int q = 0; q < 16; q += 4) {
            const float4 v = *(const float4*)(src + q);
            tile[k][nq + q + 0] = f2bf(v.x);
            tile[k][nq + q + 1] = f2bf(v.y);
            tile[k][nq + q + 2] = f2bf(v.z);
            tile[k][nq + q + 3] = f2bf(v.w);
        }
    }
    __syncthreads();
    {
        const int n = t >> 2, kq = (t & 3) * 16;
        short8 o0, o1;
        #pragma unroll
        for (int j = 0; j < 8; ++j) o0[j] = tile[kq + j][n];
        #pragma unroll
        for (int j = 0; j < 8; ++j) o1[j] = tile[kq + 8 + j][n];
        short* dst = Wo + (size_t)(nb + n) * H_ + kb + kq;
        *(short8*)dst = o0;
        *(short8*)(dst + 8) = o1;
    }
}

// ---------------- fused QKV GEMM via bf16 MFMA ----------------
// C(2048 x 2304) = Xb(2048x768 bf16) @ [Wq|Wk|Wv] (Wt is [n][k] bf16).
// BM=128, BN=64, BK=64: 4 waves, each 32x64 quadrant = 2x4 frags, 16 MFMA/iter.
// Outputs written as bf16.
#define XPITCH 68   // shorts; 136B/row -> bank shift 2/row -> conflict-free b128 reads
#define WPITCH 68

__global__ __launch_bounds__(256, 2)
void qkv_mfma(const short* __restrict__ Xb, const short* __restrict__ Wt,
              const float* __restrict__ bq, const float* __restrict__ bk,
              const float* __restrict__ bv,
              short* __restrict__ Qo, short* __restrict__ Ko, short* __restrict__ Vo)
{
    __shared__ __align__(16) short Xs[128 * XPITCH];
    __shared__ __align__(16) short Ws[64 * WPITCH];
    const int t = threadIdx.x;
    const int mt = blockIdx.x / 12;              // 0=Q,1=K,2=V
    const int n0 = (blockIdx.x % 12) * 64;
    const int m0 = blockIdx.y * 128;
    const short* Wm = Wt + (size_t)mt * H_ * H_;

    const int wave = t >> 6, lane = t & 63;
    const int quad = lane >> 4, lr = lane & 15;

    float4v acc[2][4];
    #pragma unroll
    for (int i = 0; i < 2; ++i)
        #pragma unroll
        for (int j = 0; j < 4; ++j)
            acc[i][j] = (float4v){0.f, 0.f, 0.f, 0.f};

    // X staging: 2 thr/row, each 4 interleaved short8 (32B contiguous per lane-pair)
    const int xrow = t >> 1, xoff = (t & 1) * 8;
    // W staging: 4 thr/row, each 2 short8
    const int wrow = t >> 2, woff = (t & 3) * 16;

    for (int kt = 0; kt < H_; kt += 64) {
        {
            const short* src = Xb + (size_t)(m0 + xrow) * H_ + kt + xoff;
            short* dst = &Xs[xrow * XPITCH + xoff];
            #pragma unroll
            for (int i = 0; i < 4; ++i)
                *(short8*)(dst + i * 16) = *(const short8*)(src + i * 16);
        }
        {
            const short* src = Wm + (size_t)(n0 + wrow) * H_ + kt + woff;
            short* dst = &Ws[wrow * WPITCH + woff];
            *(short8*)dst = *(const short8*)src;
            *(short8*)(dst + 8) = *(const short8*)(src + 8);
        }
        __syncthreads();

        #pragma unroll
        for (int kk = 0; kk < 2; ++kk) {
            short8 af[2], bf[4];
            #pragma unroll
            for (int i = 0; i < 2; ++i)
                af[i] = *(const short8*)&Xs[(wave * 32 + i * 16 + lr) * XPITCH + kk * 32 + quad * 8];
            #pragma unroll
            for (int j = 0; j < 4; ++j)
                bf[j] = *(const short8*)&Ws[(j * 16 + lr) * WPITCH + kk * 32 + quad * 8];
            #pragma unroll
            for (int i = 0; i < 2; ++i)
                #pragma unroll
                for (int j = 0; j < 4; ++j)
                    acc[i][j] = __builtin_amdgcn_mfma_f32_16x16x32_bf16(
                        af[i], bf[j], acc[i][j], 0, 0, 0);
        }
        __syncthreads();
    }

    const float* bp = (mt == 0) ? bq : (mt == 1) ? bk : bv;
    short*       op = (mt == 0) ? Qo : (mt == 1) ? Ko : Vo;
    #pragma unroll
    for (int j = 0; j < 4; ++j) {
        const int col = n0 + j * 16 + lr;
        const float bias = bp[col];
        #pragma unroll
        for (int i = 0; i < 2; ++i) {
            #pragma unroll
            for (int r = 0; r < 4; ++r) {
                const int row = m0 + wave * 32 + i * 16 + quad * 4 + r;
                op[(size_t)row * H_ + col] = f2bf(acc[i][j][r] + bias);
            }
        }
    }
}

// ---------------- edge attention, bf16 inputs (one block per segment) ----------------
// Phase 2: 8 lanes/edge, 8 edges/wave -> all 32 edges in one pass.
__global__ __launch_bounds__(256)
void edge_attn(const short* __restrict__ Qm, const short* __restrict__ Km,
               const short* __restrict__ Vm, const int* __restrict__ eidx,
               const short* __restrict__ Ekb, const short* __restrict__ Evb,
               float* __restrict__ out)
{
    __shared__ __align__(16) float qs[H_];
    __shared__ int   jj[DEG_];
    __shared__ int   rr[DEG_];
    __shared__ float lg[DEG_][13];

    // XCD swizzle: batch b pinned to one XCD
    const int bid = blockIdx.x;
    const int seg = ((bid & 7) << 8) | (bid >> 3);
    const int b   = seg >> 8;
    const int t   = threadIdx.x;
    const int e0  = seg * DEG_;

    // phase 1: stage Q row (bf16 -> fp32 in LDS) + indices
    if (t < 192) {
        const short4 q = *(const short4*)(Qm + (size_t)seg * H_ + t * 4);
        qs[t * 4 + 0] = bf2f(q.x);
        qs[t * 4 + 1] = bf2f(q.y);
        qs[t * 4 + 2] = bf2f(q.z);
        qs[t * 4 + 3] = bf2f(q.w);
    } else if (t < 224) {
        jj[t - 192] = eidx[2 * E_ + e0 + (t - 192)];
    } else {
        rr[t - 224] = eidx[3 * E_ + e0 + (t - 224)];
    }
    __syncthreads();

    const int wave = t >> 6, lane = t & 63;
    const int e    = wave * 8 + (lane >> 3);   // this lane's edge
    const int l8   = lane & 7;                 // dim-group within each head
    const size_t bN = (size_t)b * N_;

    {
        const int j = jj[e], r = rr[e];
        const short* kr = Km  + (bN + j) * H_ + l8 * 8;
        const short* er = Ekb + (size_t)r * H_ + l8 * 8;
        float p[NH_];
        #pragma unroll
        for (int h = 0; h < NH_; ++h) {
            const float4 qa = *(const float4*)&qs[h * 64 + l8 * 8];
            const float4 qb = *(const float4*)&qs[h * 64 + l8 * 8 + 4];
            const short8 kv = *(const short8*)(kr + h * 64);
            const short8 ev = *(const short8*)(er + h * 64);
            float s;
            s  = qa.x * (bf2f(kv[0]) + bf2f(ev[0]));
            s += qa.y * (bf2f(kv[1]) + bf2f(ev[1]));
            s += qa.z * (bf2f(kv[2]) + bf2f(ev[2]));
            s += qa.w * (bf2f(kv[3]) + bf2f(ev[3]));
            s += qb.x * (bf2f(kv[4]) + bf2f(ev[4]));
            s += qb.y * (bf2f(kv[5]) + bf2f(ev[5]));
            s += qb.z * (bf2f(kv[6]) + bf2f(ev[6]));
            s += qb.w * (bf2f(kv[7]) + bf2f(ev[7]));
            p[h] = s;
        }
        #pragma unroll
        for (int off = 4; off >= 1; off >>= 1)
            #pragma unroll
            for (int h = 0; h < NH_; ++h)
                p[h] += __shfl_xor(p[h], off);
        if (l8 == 0) {
            #pragma unroll
            for (int h = 0; h < NH_; ++h) lg[e][h] = p[h] * 0.125f;
        }
    }
    __syncthreads();

    // phase 3: softmax; (head, 16 lanes), each lane owns 2 edges
    if (t < 192) {
        const int h = t >> 4, l = t & 15;
        const float a = lg[l][h], c = lg[l + 16][h];
        float m = fmaxf(a, c);
        #pragma unroll
        for (int off = 8; off >= 1; off >>= 1) m = fmaxf(m, __shfl_xor(m, off));
        const float ea = __expf(a - m), ec = __expf(c - m);
        float z = ea + ec;
        #pragma unroll
        for (int off = 8; off >= 1; off >>= 1) z += __shfl_xor(z, off);
        const float inv = 1.f / z;
        lg[l][h] = ea * inv;
        lg[l + 16][h] = ec * inv;
    }
    __syncthreads();

    // phase 4: 192 threads, 4 dims each (dims = 4t), short4 bf16 gathers
    if (t < 192) {
        const int h = t >> 4;
        const short* vbase  = Vm + bN * H_ + 4 * t;
        const short* evbase = Evb + 4 * t;
        float4 acc = {0.f, 0.f, 0.f, 0.f};
        #pragma unroll 4
        for (int e2 = 0; e2 < DEG_; ++e2) {
            const float a = lg[e2][h];
            const short4 v  = *(const short4*)(vbase  + (size_t)jj[e2] * H_);
            const short4 ev = *(const short4*)(evbase + (size_t)rr[e2] * H_);
            acc.x += a * (bf2f(v.x) + bf2f(ev.x));
            acc.y += a * (bf2f(v.y) + bf2f(ev.y));
            acc.z += a * (bf2f(v.z) + bf2f(ev.z));
            acc.w += a * (bf2f(v.w) + bf2f(ev.w));
        }
        *(float4*)(out + (size_t)seg * H_ + 4 * t) = acc;
    }
}

extern "C" void kernel_launch(void* const* d_in, const int* in_sizes, int n_in,
                              void* d_out, int out_size, void* d_ws, size_t ws_size,
                              hipStream_t stream)
{
    const float* X    = (const float*)d_in[0];
    const int*   eidx = (const int*)  d_in[1];
    const float* Wq   = (const float*)d_in[2];
    const float* bq   = (const float*)d_in[3];
    const float* Wk   = (const float*)d_in[4];
    const float* bk   = (const float*)d_in[5];
    const float* Wv   = (const float*)d_in[6];
    const float* bv   = (const float*)d_in[7];
    const float* Ek   = (const float*)d_in[8];
    const float* Ev   = (const float*)d_in[9];
    float* out = (float*)d_out;

    // workspace layout (all bf16)
    short* Qb  = (short*)d_ws;                   // M_*H_
    short* Kb  = Qb + (size_t)M_ * H_;
    short* Vb  = Kb + (size_t)M_ * H_;
    short* Xb  = Vb + (size_t)M_ * H_;           // M_*H_
    short* Wt  = Xb + (size_t)M_ * H_;           // 3*H_*H_
    short* Ekb = Wt + (size_t)3 * H_ * H_;       // R*H_ (64*768)
    short* Evb = Ekb + (size_t)64 * H_;

    cast_flat<<<dim3(816), dim3(256), 0, stream>>>(X, Ek, Ev, Xb, Ekb, Evb);
    cast_wt<<<dim3(H_ / 64, H_ / 64, 3), dim3(256), 0, stream>>>(Wq, Wk, Wv, Wt);
    qkv_mfma<<<dim3(36, 16), dim3(256), 0, stream>>>(Xb, Wt, bq, bk, bv, Qb, Kb, Vb);
    edge_attn<<<dim3(M_), dim3(256), 0, stream>>>(Qb, Kb, Vb, eidx, Ekb, Evb, out);
}